// Round 9
// baseline (178.326 us; speedup 1.0000x reference)
//
#include <hip/hip_runtime.h>

// Problem constants (CrossAttention_73856257622246)
#define NB 4      // batch
#define QC 256    // query channels
#define SD 16384  // Z*H*W spatial per batch
#define NT 256    // tokens
#define KVC 512   // token channels
#define TC 128    // TOKEN_CH
#define NH 4      // heads
#define DH 32     // head dim
#define TSP 64    // spatial tile per block

typedef unsigned short u16;
typedef unsigned int u32;
typedef __attribute__((ext_vector_type(8))) short bf16x8;  // MFMA A/B frag (4 VGPR)
typedef __attribute__((ext_vector_type(4))) float f32x4;   // MFMA C/D frag

__device__ __forceinline__ float b2f(u16 u) {
  unsigned int v = ((unsigned int)u) << 16;
  return __builtin_bit_cast(float, v);
}
__device__ __forceinline__ u16 f2b(float f) {  // RNE
  unsigned int x = __builtin_bit_cast(unsigned int, f);
  unsigned int r = (x + 0x7fffu + ((x >> 16) & 1u)) >> 16;
  return (u16)r;
}
__device__ __forceinline__ u16 f2b_fast(float f) {  // round-half-up, 2 VALU
  return (u16)((__builtin_bit_cast(unsigned int, f) + 0x8000u) >> 16);
}
// pack bf16(a) into low16, bf16(b) into high16 — 2 adds + 1 v_perm
__device__ __forceinline__ u32 pk2(float a, float b) {
  u32 ua = __builtin_bit_cast(u32, a) + 0x8000u;
  u32 ub = __builtin_bit_cast(u32, b) + 0x8000u;
  return __builtin_amdgcn_perm(ub, ua, 0x07060302u);
}

// XOR-swizzled index, 16B granule, key=(row>>1)&7 (verified r5: conflicts
// 6.03M->4.98M vs row&7).
__device__ __forceinline__ int swz(int row, int col) {   // [64][256] u16 tile
  return (row << 8) + (col ^ (((row >> 1) & 7) << 3));
}
__device__ __forceinline__ int swzH(int row, int col) {  // [64][128] u16 tile
  return (row << 7) + (col ^ (((row >> 1) & 7) << 3));
}
// qT f32 [128 o][64 s]: swizzle s by o so b128 col-writes and row-reads spread
__device__ __forceinline__ int qidx(int o, int s) {
  return o * 64 + (s ^ ((o & 7) << 2));
}

// ---- prep: weight pre-pack (blocks 0..159) + K/V precompute (all blocks) ----
// w1p slot = (jblk*8 + kblk)*64 + lane   (jblk: 32, kblk: 8)
// w2p slot = (oblk*16 + kblk)*64 + lane  (oblk: 16, kblk: 16)
// qwp slot = (oblk*8  + kblk)*64 + lane  (oblk: 8,  kblk: 8)   [qw 128x256]
// pwp slot = (oblk*4  + kblk)*64 + lane  (oblk: 16, kblk: 4)   [projw 256x128]
__global__ __launch_bounds__(256) void prep_kernel(
    const float* __restrict__ ff1w, const float* __restrict__ ff2w,
    u16* __restrict__ w1p, u16* __restrict__ w2p,
    const float* __restrict__ qw, const float* __restrict__ projw,
    u16* __restrict__ qwp, u16* __restrict__ pwp,
    const float* __restrict__ tokens, const float* __restrict__ kw,
    const float* __restrict__ vw, const float* __restrict__ gate,
    float* __restrict__ ws_k, u16* __restrict__ ws_v) {
  int bid = blockIdx.x;
  if (bid < 160) {
    int idx = bid * 256 + threadIdx.x;  // 0..40959
    int lane = idx & 63;
    int m = lane & 15, q = lane >> 4;
    const float* src;
    u16* dst;
    if (idx < 16384) {
      int kblk = (idx >> 6) & 7;
      int jblk = idx >> 9;
      src = ff1w + (size_t)(jblk * 16 + m) * QC + kblk * 32 + q * 8;
      dst = w1p + (size_t)idx * 8;
    } else if (idx < 32768) {
      int s2 = idx - 16384;
      int kblk = (s2 >> 6) & 15;
      int oblk = s2 >> 10;
      src = ff2w + (size_t)(oblk * 16 + m) * KVC + kblk * 32 + q * 8;
      dst = w2p + (size_t)s2 * 8;
    } else if (idx < 36864) {
      int s3 = idx - 32768;
      int kblk = (s3 >> 6) & 7;
      int oblk = s3 >> 9;
      src = qw + (size_t)(oblk * 16 + m) * QC + kblk * 32 + q * 8;
      dst = qwp + (size_t)s3 * 8;
    } else {
      int s4 = idx - 36864;
      int kblk = (s4 >> 6) & 3;
      int oblk = s4 >> 8;
      src = projw + (size_t)(oblk * 16 + m) * TC + kblk * 32 + q * 8;
      dst = pwp + (size_t)s4 * 8;
    }
#pragma unroll
    for (int i = 0; i < 8; i++) dst[i] = f2b(src[i]);
  }
  // ---- K/V (only does work when tanh(gate) != 0). K fp32, V bf16. ----
  float tg = tanhf(gate[0]);
  if (tg == 0.0f) return;
  {
    int b = bid >> 8;
    int n = bid & 255;
    __shared__ float tok[KVC];
    for (int c = threadIdx.x; c < KVC; c += 256)
      tok[c] = tokens[((size_t)(b * NT + n)) * KVC + c];
    __syncthreads();
    int tid = threadIdx.x;
    int t = tid & 127;
    const float* w = (tid < 128) ? kw : vw;
    const float* wr = w + (size_t)t * KVC;
    float acc = 0.f;
    for (int c = 0; c < KVC; c += 4) {
      float4 wv = *(const float4*)(wr + c);
      acc += tok[c] * wv.x + tok[c + 1] * wv.y + tok[c + 2] * wv.z + tok[c + 3] * wv.w;
    }
    int h = t >> 5, d = t & 31;
    size_t ix = (((size_t)(b * NH + h) * NT) + n) * DH + d;
    if (tid < 128) ws_k[ix] = acc;
    else           ws_v[ix] = f2b(acc);
  }
}

// ---- fused kernel ----
// 512 threads (8 waves), __launch_bounds__(512,4) = 128 regs/wave total
// (unified VGPR/AGPR; FFN accumulators = 48 AGPR, proven no-spill r4/r7).
// Attention phase rebuilt (r7 counters: scalar attention ~100k cyc on half
// the waves dominated):
//   - Q-proj: MFMA (M=64,N=128,K=256), qw prepacked bf16 -> qT f32 in LDS
//   - softmax: 8 waves = 2 per head, 128 tokens each, fp32 K / bf16 V,
//     online merge of the two halves via LDS partials
//   - proj:   MFMA (M=64,N=256,K=128), projw prepacked bf16, fused residual
// FFN: identical to round 7 (verified): 4 chunks of 128 j, ping-pong sH,
// GEMM1 2m x 2j (16 AGPR), GEMM2 2s x 4o (32 AGPR).
// LDS 66 KB -> 2 blocks/CU = 16 waves/CU. Workspace total 1.41 MB (<=1.5 MB
// envelope proven in rounds 0-7).
__global__ __launch_bounds__(512, 4) void fused_kernel(
    const float* __restrict__ feat, const float* __restrict__ qb,
    const float* __restrict__ projb, const float* __restrict__ ff1b,
    const float* __restrict__ ff2b, const u16* __restrict__ w1p,
    const u16* __restrict__ w2p, const u16* __restrict__ qwp,
    const u16* __restrict__ pwp, const float* __restrict__ gate,
    const float* __restrict__ ws_k, const u16* __restrict__ ws_v,
    float* __restrict__ out) {
  __shared__ u16 sX[64 * 256];     // feat/out1 tile [s][c], swizzled, 32 KB
  __shared__ u16 sH[2][64 * 128];  // qT f32 / attn partials / attn bf16 / FFN
  __shared__ float sml[512];       // per-head per-s (m, l) of half-1 partials

  int b = blockIdx.x >> 8;
  int s0 = (blockIdx.x & 255) * TSP;
  int tid = threadIdx.x;
  int w = tid >> 6;     // wave 0..7
  int lane = tid & 63;
  int lm = lane & 15, lq = lane >> 4;
  int wcol = w >> 1;    // FFN: j-col (GEMM1) / o-quad (GEMM2), 0..3
  int wrow = w & 1;     // FFN: m-row (GEMM1) / s-row (GEMM2), 0..1

  // ---- stage feat tile transposed: global [c][s] fp32 -> LDS [s][c] bf16 ----
  {
    const float* fb = feat + (((size_t)b * QC) << 14) + s0;
    int cq = (tid >> 4) * 4;   // c quad base 0..124
    int sq = (tid & 15) * 4;   // s quad
#pragma unroll
    for (int it = 0; it < 2; ++it) {
      int c = it * 128 + cq;
      float4 r0 = *(const float4*)(fb + ((size_t)(c + 0) << 14) + sq);
      float4 r1 = *(const float4*)(fb + ((size_t)(c + 1) << 14) + sq);
      float4 r2 = *(const float4*)(fb + ((size_t)(c + 2) << 14) + sq);
      float4 r3 = *(const float4*)(fb + ((size_t)(c + 3) << 14) + sq);
      uint2 d0, d1, d2, d3;
      d0.x = pk2(r0.x, r1.x); d0.y = pk2(r2.x, r3.x);
      d1.x = pk2(r0.y, r1.y); d1.y = pk2(r2.y, r3.y);
      d2.x = pk2(r0.z, r1.z); d2.y = pk2(r2.z, r3.z);
      d3.x = pk2(r0.w, r1.w); d3.y = pk2(r2.w, r3.w);
      *(uint2*)&sX[swz(sq + 0, c)] = d0;
      *(uint2*)&sX[swz(sq + 1, c)] = d1;
      *(uint2*)&sX[swz(sq + 2, c)] = d2;
      *(uint2*)&sX[swz(sq + 3, c)] = d3;
    }
  }
  float tg = tanhf(gate[0]);
  __syncthreads();

  if (tg != 0.0f) {
    // ---- Q-proj MFMA: Q[s][o=128] = sX * qw^T + qb; wave w -> o-block w ----
    {
      f32x4 qa[4];
      float qbv = qb[w * 16 + lm];
#pragma unroll
      for (int m = 0; m < 4; m++) qa[m] = f32x4{qbv, qbv, qbv, qbv};
      const u16* bp = qwp + (((size_t)w * 8) * 64 + lane) * 8;
      bf16x8 c0 = *(const bf16x8*)(bp);
#pragma unroll
      for (int k = 0; k < 8; ++k) {
        bf16x8 n0;
        if (k < 7) n0 = *(const bf16x8*)(bp + (size_t)(k + 1) * 512);
        int col = k * 32 + lq * 8;
#pragma unroll
        for (int m = 0; m < 4; m++) {
          bf16x8 a = *(const bf16x8*)&sX[swz(m * 16 + lm, col)];
          qa[m] = __builtin_amdgcn_mfma_f32_16x16x32_bf16(a, c0, qa[m], 0, 0, 0);
        }
        if (k < 7) c0 = n0;
      }
      // write qT f32: lane holds col o=w*16+lm, rows m*16+lq*4+r
      float* qf = (float*)sH;
      int o = w * 16 + lm;
#pragma unroll
      for (int m = 0; m < 4; m++) {
        float4 qv = {qa[m][0], qa[m][1], qa[m][2], qa[m][3]};
        *(float4*)&qf[qidx(o, m * 16 + lq * 4)] = qv;
      }
    }
    __syncthreads();
    // ---- load my q row: head h = w&3, token-half = w>>2, s = lane ----
    int h = w & 3, half = w >> 2;
    float qreg[DH];
    {
      const float* qf = (const float*)sH;
#pragma unroll
      for (int d = 0; d < DH; d++)
        qreg[d] = qf[(h * 32 + d) * 64 + (lane ^ ((d & 7) << 2))];
    }
    __syncthreads();  // all qT reads done before partials overwrite sH
    // ---- online-softmax over my 128 tokens (K fp32, V bf16) ----
    const float* Kp = ws_k + ((size_t)(b * NH + h) * NT + half * 128) * DH;
    const u16* Vp = ws_v + ((size_t)(b * NH + h) * NT + half * 128) * DH;
    float m_ = -1e30f, l_ = 0.f;
    float oacc[DH];
#pragma unroll
    for (int d = 0; d < DH; d++) oacc[d] = 0.f;
    const float scale = 0.17677669529663687f;  // 1/sqrt(32)
    for (int n = 0; n < 128; n++) {
      const float* kr = Kp + n * DH;
      float s = 0.f;
#pragma unroll
      for (int d = 0; d < DH; d++) s += qreg[d] * kr[d];
      s *= scale;
      float nm = fmaxf(m_, s);
      float p = __expf(s - nm);
      float al = __expf(m_ - nm);
      const u16* vr = Vp + n * DH;
      u16 vbuf[DH];
      *(uint4*)&vbuf[0]  = *(const uint4*)(vr);
      *(uint4*)&vbuf[8]  = *(const uint4*)(vr + 8);
      *(uint4*)&vbuf[16] = *(const uint4*)(vr + 16);
      *(uint4*)&vbuf[24] = *(const uint4*)(vr + 24);
      l_ = l_ * al + p;
#pragma unroll
      for (int d = 0; d < DH; d++) oacc[d] = oacc[d] * al + p * b2f(vbuf[d]);
      m_ = nm;
    }
    // ---- half-1 publishes partials (oacc, m, l) ----
    float* pb = (float*)sH + h * 2048;
    int smask = (lane & 7) << 2;
    if (half == 1) {
#pragma unroll
      for (int g = 0; g < 8; g++) {
        float4 pv = {oacc[g * 4], oacc[g * 4 + 1], oacc[g * 4 + 2], oacc[g * 4 + 3]};
        *(float4*)&pb[lane * 32 + ((g * 4) ^ smask)] = pv;
      }
      sml[h * 128 + lane * 2] = m_;
      sml[h * 128 + lane * 2 + 1] = l_;
    }
    __syncthreads();
    // ---- half-0 merges and normalizes ----
    if (half == 0) {
      float m1 = sml[h * 128 + lane * 2];
      float l1 = sml[h * 128 + lane * 2 + 1];
      float M = fmaxf(m_, m1);
      float a0 = __expf(m_ - M), a1 = __expf(m1 - M);
      float inv = 1.0f / (l_ * a0 + l1 * a1);
#pragma unroll
      for (int g = 0; g < 8; g++) {
        float4 pv = *(const float4*)&pb[lane * 32 + ((g * 4) ^ smask)];
#pragma unroll
        for (int r = 0; r < 4; r++)
          oacc[g * 4 + r] = (oacc[g * 4 + r] * a0 + pv[r] * a1) * inv;
      }
    }
    __syncthreads();  // all partial reads done before attn-out overwrites sH
    // ---- half-0 writes attn bf16 [s][t=128] into sH[0..16KB) ----
    if (half == 0) {
      u16* sa = (u16*)sH;
#pragma unroll
      for (int dd = 0; dd < 16; dd++) {
        u32 v = pk2(oacc[2 * dd], oacc[2 * dd + 1]);
        *(u32*)&sa[swzH(lane, h * 32 + 2 * dd)] = v;
      }
    }
    __syncthreads();
    // ---- proj MFMA + gated residual: wave w -> o-blocks {2w, 2w+1} ----
    {
      f32x4 pa[2][4];
#pragma unroll
      for (int t = 0; t < 2; t++) {
        float pbv = projb[(w * 2 + t) * 16 + lm];
#pragma unroll
        for (int m = 0; m < 4; m++) pa[t][m] = f32x4{pbv, pbv, pbv, pbv};
      }
      const u16* bp0 = pwp + (((size_t)(w * 2) * 4) * 64 + lane) * 8;
      const u16* bp1 = bp0 + 2048;  // next o-block (4 kblks * 512)
      bf16x8 c0 = *(const bf16x8*)(bp0);
      bf16x8 c1 = *(const bf16x8*)(bp1);
      const u16* sa = (const u16*)sH;
#pragma unroll
      for (int k = 0; k < 4; ++k) {
        bf16x8 n0, n1;
        if (k < 3) {
          n0 = *(const bf16x8*)(bp0 + (size_t)(k + 1) * 512);
          n1 = *(const bf16x8*)(bp1 + (size_t)(k + 1) * 512);
        }
        int col = k * 32 + lq * 8;
#pragma unroll
        for (int m = 0; m < 4; m++) {
          bf16x8 a = *(const bf16x8*)&sa[swzH(m * 16 + lm, col)];
          pa[0][m] = __builtin_amdgcn_mfma_f32_16x16x32_bf16(a, c0, pa[0][m], 0, 0, 0);
          pa[1][m] = __builtin_amdgcn_mfma_f32_16x16x32_bf16(a, c1, pa[1][m], 0, 0, 0);
        }
        if (k < 3) { c0 = n0; c1 = n1; }
      }
      // gated residual RMW into sX (each lane owns distinct (row,col) slots)
#pragma unroll
      for (int t = 0; t < 2; t++) {
        int c = (w * 2 + t) * 16 + lm;
#pragma unroll
        for (int m = 0; m < 4; m++) {
#pragma unroll
          for (int r = 0; r < 4; r++) {
            int row = m * 16 + lq * 4 + r;
            int ix = swz(row, c);
            sX[ix] = f2b(b2f(sX[ix]) + tg * pa[t][m][r]);
          }
        }
      }
    }
    __syncthreads();
  }

  // ==== FFN (identical to round 7, verified) ====
  f32x4 acc2[4][2];  // [t = o-block in quad][mi = s-block], persists
#pragma unroll
  for (int t = 0; t < 4; t++) {
    float b2v = ff2b[(wcol * 4 + t) * 16 + lm];
    f32x4 iv = {b2v, b2v, b2v, b2v};
#pragma unroll
    for (int mi = 0; mi < 2; mi++) acc2[t][mi] = iv;
  }

#pragma unroll 1
  for (int ch = 0; ch < 4; ++ch) {
    u16* sHh = sH[ch & 1];
    // ---- GEMM1: wave tile = m-blocks {wrow*2,+1} x j-blocks {ch*8+wcol*2,+1}
    f32x4 acc1[2][2];  // [jt][mi]
#pragma unroll
    for (int jt = 0; jt < 2; jt++) {
      float b1v = ff1b[(ch * 8 + wcol * 2 + jt) * 16 + lm];
      f32x4 iv = {b1v, b1v, b1v, b1v};
#pragma unroll
      for (int mi = 0; mi < 2; mi++) acc1[jt][mi] = iv;
    }
    {
      int jb0 = ch * 8 + wcol * 2;
      const u16* p0 = w1p + (((size_t)jb0 * 8) * 64 + lane) * 8;
      const u16* p1 = p0 + 4096;  // next j-block (8 kblks * 512)
      bf16x8 c0 = *(const bf16x8*)(p0);
      bf16x8 c1 = *(const bf16x8*)(p1);
#pragma unroll
      for (int k = 0; k < 8; ++k) {
        bf16x8 n0, n1;
        if (k < 7) {
          n0 = *(const bf16x8*)(p0 + (size_t)(k + 1) * 512);
          n1 = *(const bf16x8*)(p1 + (size_t)(k + 1) * 512);
        }
        int col = k * 32 + lq * 8;
#pragma unroll
        for (int mi = 0; mi < 2; mi++) {
          bf16x8 a = *(const bf16x8*)&sX[swz((wrow * 2 + mi) * 16 + lm, col)];
          acc1[0][mi] = __builtin_amdgcn_mfma_f32_16x16x32_bf16(a, c0, acc1[0][mi], 0, 0, 0);
          acc1[1][mi] = __builtin_amdgcn_mfma_f32_16x16x32_bf16(a, c1, acc1[1][mi], 0, 0, 0);
        }
        if (k < 7) { c0 = n0; c1 = n1; }
      }
    }
    // SiLU -> sHh; safe pre-barrier (ping-pong: only racing reader is
    // GEMM2(ch-2), complete before barrier(ch-1))
#pragma unroll
    for (int jt = 0; jt < 2; jt++) {
      int jl = (wcol * 2 + jt) * 16 + lm;
#pragma unroll
      for (int mi = 0; mi < 2; mi++) {
        int sb = (wrow * 2 + mi) * 16 + lq * 4;
        f32x4 v = acc1[jt][mi];
#pragma unroll
        for (int r = 0; r < 4; r++) {
          float x = v[r];
          float sl = x * __builtin_amdgcn_rcpf(1.f + __expf(-x));
          sHh[swzH(sb + r, jl)] = f2b_fast(sl);
        }
      }
    }
    // GEMM2 first k-step weights loaded BEFORE the barrier: latency hides
    const u16* qp = w2p + (((size_t)(wcol * 4) * 16 + ch * 4) * 64 + lane) * 8;
    bf16x8 d0 = *(const bf16x8*)(qp);
    bf16x8 d1 = *(const bf16x8*)(qp + 8192);      // o-block stride = 16*512
    bf16x8 d2 = *(const bf16x8*)(qp + 16384);
    bf16x8 d3 = *(const bf16x8*)(qp + 24576);
    __syncthreads();  // sHh ready
    // ---- GEMM2 partial: K = this 128-j chunk (4 k-steps) ----
#pragma unroll
    for (int k = 0; k < 4; ++k) {
      bf16x8 e0, e1, e2, e3;
      if (k < 3) {
        e0 = *(const bf16x8*)(qp + (size_t)(k + 1) * 512);
        e1 = *(const bf16x8*)(qp + 8192 + (size_t)(k + 1) * 512);
        e2 = *(const bf16x8*)(qp + 16384 + (size_t)(k + 1) * 512);
        e3 = *(const bf16x8*)(qp + 24576 + (size_t)(k + 1) * 512);
      }
      int col = k * 32 + lq * 8;
#pragma unroll
      for (int mi = 0; mi < 2; mi++) {
        bf16x8 a = *(const bf16x8*)&sHh[swzH((wrow * 2 + mi) * 16 + lm, col)];
        acc2[0][mi] = __builtin_amdgcn_mfma_f32_16x16x32_bf16(a, d0, acc2[0][mi], 0, 0, 0);
        acc2[1][mi] = __builtin_amdgcn_mfma_f32_16x16x32_bf16(a, d1, acc2[1][mi], 0, 0, 0);
        acc2[2][mi] = __builtin_amdgcn_mfma_f32_16x16x32_bf16(a, d2, acc2[2][mi], 0, 0, 0);
        acc2[3][mi] = __builtin_amdgcn_mfma_f32_16x16x32_bf16(a, d3, acc2[3][mi], 0, 0, 0);
      }
      if (k < 3) { d0 = e0; d1 = e1; d2 = e2; d3 = e3; }
    }
  }

  // ---- epilogue: out[c][s] = out1 + ff (bias already in acc2) ----
#pragma unroll
  for (int t = 0; t < 4; t++) {
    int c = (wcol * 4 + t) * 16 + lm;
#pragma unroll
    for (int mi = 0; mi < 2; mi++) {
      int sb = (wrow * 2 + mi) * 16 + lq * 4;
      f32x4 v = acc2[t][mi];
      float4 ov;
      ov.x = v[0] + b2f(sX[swz(sb + 0, c)]);
      ov.y = v[1] + b2f(sX[swz(sb + 1, c)]);
      ov.z = v[2] + b2f(sX[swz(sb + 2, c)]);
      ov.w = v[3] + b2f(sX[swz(sb + 3, c)]);
      *(float4*)(out + (((size_t)(b * QC + c)) << 14) + s0 + sb) = ov;
    }
  }
}

extern "C" void kernel_launch(void* const* d_in, const int* in_sizes, int n_in,
                              void* d_out, int out_size, void* d_ws, size_t ws_size,
                              hipStream_t stream) {
  const float* feat   = (const float*)d_in[0];
  const float* tokens = (const float*)d_in[1];
  const float* qw     = (const float*)d_in[2];
  const float* qb     = (const float*)d_in[3];
  const float* kw     = (const float*)d_in[4];
  const float* vw     = (const float*)d_in[5];
  const float* projw  = (const float*)d_in[6];
  const float* projb  = (const float*)d_in[7];
  const float* ff1w   = (const float*)d_in[8];
  const float* ff1b   = (const float*)d_in[9];
  const float* ff2w   = (const float*)d_in[10];
  const float* ff2b   = (const float*)d_in[11];
  const float* gate   = (const float*)d_in[12];
  float* out = (float*)d_out;

  // Workspace layout — total 1.41 MB (within the 1.5 MB envelope proven r0-r7)
  u16* w1p = (u16*)d_ws;                               // 256 KB @ 0
  u16* w2p = w1p + 131072;                             // 256 KB @ 256K
  u16* qwp = w2p + 131072;                             //  64 KB @ 512K
  u16* pwp = qwp + 32768;                              //  64 KB @ 576K
  float* ws_k = (float*)((char*)d_ws + 655360);        // 512 KB @ 640K (K f32)
  u16* ws_v = (u16*)((char*)d_ws + 1179648);           // 256 KB @1152K (V bf16)

  prep_kernel<<<dim3(NB * NT), dim3(256), 0, stream>>>(
      ff1w, ff2w, w1p, w2p, qw, projw, qwp, pwp, tokens, kw, vw, gate,
      ws_k, ws_v);
  fused_kernel<<<dim3(NB * (SD / TSP)), dim3(512), 0, stream>>>(
      feat, qb, projb, ff1b, ff2b, w1p, w2p, qwp, pwp, gate, ws_k, ws_v, out);
}

// Round 10
// 176.715 us; speedup vs baseline: 1.0091x; 1.0091x over previous
//
#include <hip/hip_runtime.h>

// Problem constants (CrossAttention_73856257622246)
#define NB 4      // batch
#define QC 256    // query channels
#define SD 16384  // Z*H*W spatial per batch
#define NT 256    // tokens
#define KVC 512   // token channels
#define TC 128    // TOKEN_CH
#define NH 4      // heads
#define DH 32     // head dim
#define TSP 64    // spatial tile per block

typedef unsigned short u16;
typedef unsigned int u32;
typedef __attribute__((ext_vector_type(8))) short bf16x8;  // MFMA A/B frag (4 VGPR)
typedef __attribute__((ext_vector_type(4))) float f32x4;   // MFMA C/D frag

__device__ __forceinline__ float b2f(u16 u) {
  unsigned int v = ((unsigned int)u) << 16;
  return __builtin_bit_cast(float, v);
}
__device__ __forceinline__ u16 f2b(float f) {  // RNE
  unsigned int x = __builtin_bit_cast(unsigned int, f);
  unsigned int r = (x + 0x7fffu + ((x >> 16) & 1u)) >> 16;
  return (u16)r;
}
__device__ __forceinline__ u16 f2b_fast(float f) {  // round-half-up, 2 VALU
  return (u16)((__builtin_bit_cast(unsigned int, f) + 0x8000u) >> 16);
}
// pack bf16(a) into low16, bf16(b) into high16 — 2 adds + 1 v_perm
__device__ __forceinline__ u32 pk2(float a, float b) {
  u32 ua = __builtin_bit_cast(u32, a) + 0x8000u;
  u32 ub = __builtin_bit_cast(u32, b) + 0x8000u;
  return __builtin_amdgcn_perm(ub, ua, 0x07060302u);
}

// XOR-swizzled index, 16B granule, key=(row>>1)&7 (verified r5: conflicts
// 6.03M->4.98M vs row&7).
__device__ __forceinline__ int swz(int row, int col) {   // [64][256] u16 tile
  return (row << 8) + (col ^ (((row >> 1) & 7) << 3));
}
__device__ __forceinline__ int swzH(int row, int col) {  // [64][128] u16 tile
  return (row << 7) + (col ^ (((row >> 1) & 7) << 3));
}
// P buffer [32 s][32 t] u16, 16B-granule swizzle keyed by lq=(s>>2)&3
__device__ __forceinline__ int pswz(int s, int t) {
  return (s << 5) + (t ^ (((s >> 2) & 3) << 3));
}

// ---- prep: weight pre-pack (blocks 0..159) + K/V precompute (all blocks) ----
// w1p slot = (jblk*8 + kblk)*64 + lane   (jblk: 32, kblk: 8)
// w2p slot = (oblk*16 + kblk)*64 + lane  (oblk: 16, kblk: 16)
// qwp slot = (oblk*8  + kblk)*64 + lane  (oblk: 8,  kblk: 8)   [qw 128x256]
// pwp slot = (oblk*4  + kblk)*64 + lane  (oblk: 16, kblk: 4)   [projw 256x128]
// Kbp: B-frag layout for S=Q*K^T: B[k=d][n=t]; slot=(bh*16+tblk)*512+lane*8+i
//      with t=tblk*16+(lane&15), d=(lane>>4)*8+i
// Vbp: B-frag layout for O=P*V:   B[k=t][n=d]; slot=(bh*16+t32*2+dhi)*512+...
//      with d=dhi*16+(lane&15), t_local=(lane>>4)*8+i
__global__ __launch_bounds__(256) void prep_kernel(
    const float* __restrict__ ff1w, const float* __restrict__ ff2w,
    u16* __restrict__ w1p, u16* __restrict__ w2p,
    const float* __restrict__ qw, const float* __restrict__ projw,
    u16* __restrict__ qwp, u16* __restrict__ pwp,
    const float* __restrict__ tokens, const float* __restrict__ kw,
    const float* __restrict__ vw, const float* __restrict__ gate,
    u16* __restrict__ Kbp, u16* __restrict__ Vbp) {
  int bid = blockIdx.x;
  if (bid < 160) {
    int idx = bid * 256 + threadIdx.x;  // 0..40959
    int lane = idx & 63;
    int m = lane & 15, q = lane >> 4;
    const float* src;
    u16* dst;
    if (idx < 16384) {
      int kblk = (idx >> 6) & 7;
      int jblk = idx >> 9;
      src = ff1w + (size_t)(jblk * 16 + m) * QC + kblk * 32 + q * 8;
      dst = w1p + (size_t)idx * 8;
    } else if (idx < 32768) {
      int s2 = idx - 16384;
      int kblk = (s2 >> 6) & 15;
      int oblk = s2 >> 10;
      src = ff2w + (size_t)(oblk * 16 + m) * KVC + kblk * 32 + q * 8;
      dst = w2p + (size_t)s2 * 8;
    } else if (idx < 36864) {
      int s3 = idx - 32768;
      int kblk = (s3 >> 6) & 7;
      int oblk = s3 >> 9;
      src = qw + (size_t)(oblk * 16 + m) * QC + kblk * 32 + q * 8;
      dst = qwp + (size_t)s3 * 8;
    } else {
      int s4 = idx - 36864;
      int kblk = (s4 >> 6) & 3;
      int oblk = s4 >> 8;
      src = projw + (size_t)(oblk * 16 + m) * TC + kblk * 32 + q * 8;
      dst = pwp + (size_t)s4 * 8;
    }
#pragma unroll
    for (int i = 0; i < 8; i++) dst[i] = f2b(src[i]);
  }
  // ---- K/V (only does work when tanh(gate) != 0); packed bf16 B-frags ----
  float tg = tanhf(gate[0]);
  if (tg == 0.0f) return;
  {
    int b = bid >> 8;
    int n = bid & 255;  // token
    __shared__ float tok[KVC];
    for (int c = threadIdx.x; c < KVC; c += 256)
      tok[c] = tokens[((size_t)(b * NT + n)) * KVC + c];
    __syncthreads();
    int tid = threadIdx.x;
    int t = tid & 127;
    const float* w = (tid < 128) ? kw : vw;
    const float* wr = w + (size_t)t * KVC;
    float acc = 0.f;
    for (int c = 0; c < KVC; c += 4) {
      float4 wv = *(const float4*)(wr + c);
      acc += tok[c] * wv.x + tok[c + 1] * wv.y + tok[c + 2] * wv.z + tok[c + 3] * wv.w;
    }
    int h = t >> 5, d = t & 31;
    int bh = b * NH + h;
    if (tid < 128) {
      size_t ix = (size_t)(bh * 16 + (n >> 4)) * 512 +
                  (((n & 15) | ((d >> 3) << 4)) << 3) + (d & 7);
      Kbp[ix] = f2b(acc);
    } else {
      size_t ix = (size_t)(bh * 16 + (n >> 5) * 2 + (d >> 4)) * 512 +
                  (((d & 15) | (((n >> 3) & 3) << 4)) << 3) + (n & 7);
      Vbp[ix] = f2b(acc);
    }
  }
}

// ---- fused kernel ----
// 512 threads (8 waves), __launch_bounds__(512,4) = 128 regs/wave total
// (unified VGPR/AGPR; FFN accumulators = 48 AGPR, proven no-spill r4/r7).
// Round-10: attention FLOPs moved to MFMA (r9 showed softmax VALU throughput
// ~100k cycles/SIMD dominated). Per wave = one (head, s-half): 32 s x 256 t,
// 8 chunks of 32 t, flash-style online softmax (s-split -> no cross-wave
// merge). S = MFMA(Q, Kbp); row max/sum via shfl_xor over 16-lane t-groups;
// P -> wave-private LDS (2 KB, pswz) -> A-frag; O = MFMA(P, Vbp) with VALU
// rescale. Q bf16 (scale folded), K/V bf16 packed by prep.
// Attn-out overwrites Q LDS region in place (disjoint per-wave blocks).
// proj + residual + FFN identical to r7/r9 (verified).
// LDS 64 KB -> 2 blocks/CU = 16 waves/CU.
__global__ __launch_bounds__(512, 4) void fused_kernel(
    const float* __restrict__ feat, const float* __restrict__ qb,
    const float* __restrict__ projb, const float* __restrict__ ff1b,
    const float* __restrict__ ff2b, const u16* __restrict__ w1p,
    const u16* __restrict__ w2p, const u16* __restrict__ qwp,
    const u16* __restrict__ pwp, const float* __restrict__ gate,
    const u16* __restrict__ Kbp, const u16* __restrict__ Vbp,
    float* __restrict__ out) {
  __shared__ u16 sX[64 * 256];     // feat/out1 tile [s][c], swizzled, 32 KB
  __shared__ u16 sH[2][64 * 128];  // sQ/attn-out + P bufs; FFN ping-pong

  int b = blockIdx.x >> 8;
  int s0 = (blockIdx.x & 255) * TSP;
  int tid = threadIdx.x;
  int w = tid >> 6;     // wave 0..7
  int lane = tid & 63;
  int lm = lane & 15, lq = lane >> 4;
  int wcol = w >> 1;    // FFN: j-col (GEMM1) / o-quad (GEMM2), 0..3
  int wrow = w & 1;     // FFN: m-row (GEMM1) / s-row (GEMM2), 0..1

  // ---- stage feat tile transposed: global [c][s] fp32 -> LDS [s][c] bf16 ----
  {
    const float* fb = feat + (((size_t)b * QC) << 14) + s0;
    int cq = (tid >> 4) * 4;   // c quad base 0..124
    int sq = (tid & 15) * 4;   // s quad
#pragma unroll
    for (int it = 0; it < 2; ++it) {
      int c = it * 128 + cq;
      float4 r0 = *(const float4*)(fb + ((size_t)(c + 0) << 14) + sq);
      float4 r1 = *(const float4*)(fb + ((size_t)(c + 1) << 14) + sq);
      float4 r2 = *(const float4*)(fb + ((size_t)(c + 2) << 14) + sq);
      float4 r3 = *(const float4*)(fb + ((size_t)(c + 3) << 14) + sq);
      uint2 d0, d1, d2, d3;
      d0.x = pk2(r0.x, r1.x); d0.y = pk2(r2.x, r3.x);
      d1.x = pk2(r0.y, r1.y); d1.y = pk2(r2.y, r3.y);
      d2.x = pk2(r0.z, r1.z); d2.y = pk2(r2.z, r3.z);
      d3.x = pk2(r0.w, r1.w); d3.y = pk2(r2.w, r3.w);
      *(uint2*)&sX[swz(sq + 0, c)] = d0;
      *(uint2*)&sX[swz(sq + 1, c)] = d1;
      *(uint2*)&sX[swz(sq + 2, c)] = d2;
      *(uint2*)&sX[swz(sq + 3, c)] = d3;
    }
  }
  float tg = tanhf(gate[0]);
  __syncthreads();

  if (tg != 0.0f) {
    u16* sQ = &sH[0][0];  // [64 s][128 o] bf16, swzH; later holds attn-out
    // ---- Q-proj MFMA: Q[s][o=128] = sX * qw^T + qb; wave w -> o-block w ----
    {
      f32x4 qa[4];
      float qbv = qb[w * 16 + lm];
#pragma unroll
      for (int m = 0; m < 4; m++) qa[m] = f32x4{qbv, qbv, qbv, qbv};
      const u16* bp = qwp + (((size_t)w * 8) * 64 + lane) * 8;
      bf16x8 c0 = *(const bf16x8*)(bp);
#pragma unroll
      for (int k = 0; k < 8; ++k) {
        bf16x8 n0;
        if (k < 7) n0 = *(const bf16x8*)(bp + (size_t)(k + 1) * 512);
        int col = k * 32 + lq * 8;
#pragma unroll
        for (int m = 0; m < 4; m++) {
          bf16x8 a = *(const bf16x8*)&sX[swz(m * 16 + lm, col)];
          qa[m] = __builtin_amdgcn_mfma_f32_16x16x32_bf16(a, c0, qa[m], 0, 0, 0);
        }
        if (k < 7) c0 = n0;
      }
      // write bf16 Q * softmax-scale (folded): lane col o=w*16+lm
      const float QS = 0.17677669529663687f;  // 1/sqrt(32)
      int o = w * 16 + lm;
#pragma unroll
      for (int m = 0; m < 4; m++)
#pragma unroll
        for (int r = 0; r < 4; r++)
          sQ[swzH(m * 16 + lq * 4 + r, o)] = f2b(qa[m][r] * QS);
    }
    __syncthreads();

    // ---- MFMA flash attention: wave = (head h, s-half) ----
    int h = w & 3;
    int sbase = (w >> 2) * 32;
    const u16* Kb = Kbp + (size_t)(b * NH + h) * 16 * 512;
    const u16* Vb = Vbp + (size_t)(b * NH + h) * 16 * 512;
    u16* Pb = &sH[1][w * 1024];  // wave-private [32 s][32 t] bf16

    // Q A-frags (invariant across chunks)
    bf16x8 qa0 = *(const bf16x8*)&sQ[swzH(sbase + lm, h * 32 + lq * 8)];
    bf16x8 qa1 = *(const bf16x8*)&sQ[swzH(sbase + 16 + lm, h * 32 + lq * 8)];

    f32x4 O[2][2];
    float mreg[2][4], lreg[2][4];
#pragma unroll
    for (int m = 0; m < 2; m++) {
#pragma unroll
      for (int dn = 0; dn < 2; dn++) O[m][dn] = f32x4{0.f, 0.f, 0.f, 0.f};
#pragma unroll
      for (int r = 0; r < 4; r++) { mreg[m][r] = -1e30f; lreg[m][r] = 0.f; }
    }

#pragma unroll 1
    for (int tc = 0; tc < 8; ++tc) {
      bf16x8 kb0 = *(const bf16x8*)(Kb + (size_t)(tc * 2 + 0) * 512 + lane * 8);
      bf16x8 kb1 = *(const bf16x8*)(Kb + (size_t)(tc * 2 + 1) * 512 + lane * 8);
      f32x4 z = {0.f, 0.f, 0.f, 0.f};
      f32x4 S[2][2];
      S[0][0] = __builtin_amdgcn_mfma_f32_16x16x32_bf16(qa0, kb0, z, 0, 0, 0);
      S[0][1] = __builtin_amdgcn_mfma_f32_16x16x32_bf16(qa0, kb1, z, 0, 0, 0);
      S[1][0] = __builtin_amdgcn_mfma_f32_16x16x32_bf16(qa1, kb0, z, 0, 0, 0);
      S[1][1] = __builtin_amdgcn_mfma_f32_16x16x32_bf16(qa1, kb1, z, 0, 0, 0);
      // row max over 32 t: in-lane over n, then 16-lane t-group reduce
      float mx[2][4];
#pragma unroll
      for (int m = 0; m < 2; m++)
#pragma unroll
        for (int r = 0; r < 4; r++) mx[m][r] = fmaxf(S[m][0][r], S[m][1][r]);
#pragma unroll
      for (int msk = 1; msk < 16; msk <<= 1)
#pragma unroll
        for (int m = 0; m < 2; m++)
#pragma unroll
          for (int r = 0; r < 4; r++)
            mx[m][r] = fmaxf(mx[m][r], __shfl_xor(mx[m][r], msk, 64));
      float al[2][4], rs[2][4];
#pragma unroll
      for (int m = 0; m < 2; m++)
#pragma unroll
        for (int r = 0; r < 4; r++) {
          float nm = fmaxf(mreg[m][r], mx[m][r]);
          al[m][r] = __expf(mreg[m][r] - nm);
          mreg[m][r] = nm;
        }
      // P = exp(S - m), write wave-private LDS, partial row-sum
#pragma unroll
      for (int m = 0; m < 2; m++)
#pragma unroll
        for (int r = 0; r < 4; r++) {
          float p0 = __expf(S[m][0][r] - mreg[m][r]);
          float p1 = __expf(S[m][1][r] - mreg[m][r]);
          int srow = m * 16 + lq * 4 + r;
          Pb[pswz(srow, lm)] = f2b_fast(p0);
          Pb[pswz(srow, 16 + lm)] = f2b_fast(p1);
          rs[m][r] = p0 + p1;
        }
#pragma unroll
      for (int msk = 1; msk < 16; msk <<= 1)
#pragma unroll
        for (int m = 0; m < 2; m++)
#pragma unroll
          for (int r = 0; r < 4; r++)
            rs[m][r] += __shfl_xor(rs[m][r], msk, 64);
#pragma unroll
      for (int m = 0; m < 2; m++)
#pragma unroll
        for (int r = 0; r < 4; r++)
          lreg[m][r] = lreg[m][r] * al[m][r] + rs[m][r];
      // rescale O, then PV MFMA
#pragma unroll
      for (int m = 0; m < 2; m++)
#pragma unroll
        for (int dn = 0; dn < 2; dn++)
#pragma unroll
          for (int r = 0; r < 4; r++) O[m][dn][r] *= al[m][r];
      bf16x8 vb0 = *(const bf16x8*)(Vb + (size_t)(tc * 2 + 0) * 512 + lane * 8);
      bf16x8 vb1 = *(const bf16x8*)(Vb + (size_t)(tc * 2 + 1) * 512 + lane * 8);
      bf16x8 pa0 = *(const bf16x8*)&Pb[pswz(lm, lq * 8)];
      bf16x8 pa1 = *(const bf16x8*)&Pb[pswz(16 + lm, lq * 8)];
      O[0][0] = __builtin_amdgcn_mfma_f32_16x16x32_bf16(pa0, vb0, O[0][0], 0, 0, 0);
      O[0][1] = __builtin_amdgcn_mfma_f32_16x16x32_bf16(pa0, vb1, O[0][1], 0, 0, 0);
      O[1][0] = __builtin_amdgcn_mfma_f32_16x16x32_bf16(pa1, vb0, O[1][0], 0, 0, 0);
      O[1][1] = __builtin_amdgcn_mfma_f32_16x16x32_bf16(pa1, vb1, O[1][1], 0, 0, 0);
    }
    // normalize + write attn-out bf16 in place over this wave's Q block
#pragma unroll
    for (int m = 0; m < 2; m++)
#pragma unroll
      for (int r = 0; r < 4; r++) {
        float inv = 1.0f / lreg[m][r];
        int srow = sbase + m * 16 + lq * 4 + r;
#pragma unroll
        for (int dn = 0; dn < 2; dn++)
          sQ[swzH(srow, h * 32 + dn * 16 + lm)] = f2b(O[m][dn][r] * inv);
      }
    __syncthreads();

    // ---- proj MFMA + gated residual: wave w -> o-blocks {2w, 2w+1} ----
    {
      f32x4 pa[2][4];
#pragma unroll
      for (int t = 0; t < 2; t++) {
        float pbv = projb[(w * 2 + t) * 16 + lm];
#pragma unroll
        for (int m = 0; m < 4; m++) pa[t][m] = f32x4{pbv, pbv, pbv, pbv};
      }
      const u16* bp0 = pwp + (((size_t)(w * 2) * 4) * 64 + lane) * 8;
      const u16* bp1 = bp0 + 2048;  // next o-block (4 kblks * 512)
      bf16x8 c0 = *(const bf16x8*)(bp0);
      bf16x8 c1 = *(const bf16x8*)(bp1);
      const u16* sa = (const u16*)sH;  // attn-out [64][128] swzH
#pragma unroll
      for (int k = 0; k < 4; ++k) {
        bf16x8 n0, n1;
        if (k < 3) {
          n0 = *(const bf16x8*)(bp0 + (size_t)(k + 1) * 512);
          n1 = *(const bf16x8*)(bp1 + (size_t)(k + 1) * 512);
        }
        int col = k * 32 + lq * 8;
#pragma unroll
        for (int m = 0; m < 4; m++) {
          bf16x8 a = *(const bf16x8*)&sa[swzH(m * 16 + lm, col)];
          pa[0][m] = __builtin_amdgcn_mfma_f32_16x16x32_bf16(a, c0, pa[0][m], 0, 0, 0);
          pa[1][m] = __builtin_amdgcn_mfma_f32_16x16x32_bf16(a, c1, pa[1][m], 0, 0, 0);
        }
        if (k < 3) { c0 = n0; c1 = n1; }
      }
      // gated residual RMW into sX (each lane owns distinct (row,col) slots)
#pragma unroll
      for (int t = 0; t < 2; t++) {
        int c = (w * 2 + t) * 16 + lm;
#pragma unroll
        for (int m = 0; m < 4; m++) {
#pragma unroll
          for (int r = 0; r < 4; r++) {
            int row = m * 16 + lq * 4 + r;
            int ix = swz(row, c);
            sX[ix] = f2b(b2f(sX[ix]) + tg * pa[t][m][r]);
          }
        }
      }
    }
    __syncthreads();
  }

  // ==== FFN (identical to round 7, verified) ====
  f32x4 acc2[4][2];  // [t = o-block in quad][mi = s-block], persists
#pragma unroll
  for (int t = 0; t < 4; t++) {
    float b2v = ff2b[(wcol * 4 + t) * 16 + lm];
    f32x4 iv = {b2v, b2v, b2v, b2v};
#pragma unroll
    for (int mi = 0; mi < 2; mi++) acc2[t][mi] = iv;
  }

#pragma unroll 1
  for (int ch = 0; ch < 4; ++ch) {
    u16* sHh = sH[ch & 1];
    // ---- GEMM1: wave tile = m-blocks {wrow*2,+1} x j-blocks {ch*8+wcol*2,+1}
    f32x4 acc1[2][2];  // [jt][mi]
#pragma unroll
    for (int jt = 0; jt < 2; jt++) {
      float b1v = ff1b[(ch * 8 + wcol * 2 + jt) * 16 + lm];
      f32x4 iv = {b1v, b1v, b1v, b1v};
#pragma unroll
      for (int mi = 0; mi < 2; mi++) acc1[jt][mi] = iv;
    }
    {
      int jb0 = ch * 8 + wcol * 2;
      const u16* p0 = w1p + (((size_t)jb0 * 8) * 64 + lane) * 8;
      const u16* p1 = p0 + 4096;  // next j-block (8 kblks * 512)
      bf16x8 c0 = *(const bf16x8*)(p0);
      bf16x8 c1 = *(const bf16x8*)(p1);
#pragma unroll
      for (int k = 0; k < 8; ++k) {
        bf16x8 n0, n1;
        if (k < 7) {
          n0 = *(const bf16x8*)(p0 + (size_t)(k + 1) * 512);
          n1 = *(const bf16x8*)(p1 + (size_t)(k + 1) * 512);
        }
        int col = k * 32 + lq * 8;
#pragma unroll
        for (int mi = 0; mi < 2; mi++) {
          bf16x8 a = *(const bf16x8*)&sX[swz((wrow * 2 + mi) * 16 + lm, col)];
          acc1[0][mi] = __builtin_amdgcn_mfma_f32_16x16x32_bf16(a, c0, acc1[0][mi], 0, 0, 0);
          acc1[1][mi] = __builtin_amdgcn_mfma_f32_16x16x32_bf16(a, c1, acc1[1][mi], 0, 0, 0);
        }
        if (k < 7) { c0 = n0; c1 = n1; }
      }
    }
    // SiLU -> sHh; safe pre-barrier (ping-pong: only racing reader is
    // GEMM2(ch-2), complete before barrier(ch-1))
#pragma unroll
    for (int jt = 0; jt < 2; jt++) {
      int jl = (wcol * 2 + jt) * 16 + lm;
#pragma unroll
      for (int mi = 0; mi < 2; mi++) {
        int sb = (wrow * 2 + mi) * 16 + lq * 4;
        f32x4 v = acc1[jt][mi];
#pragma unroll
        for (int r = 0; r < 4; r++) {
          float x = v[r];
          float sl = x * __builtin_amdgcn_rcpf(1.f + __expf(-x));
          sHh[swzH(sb + r, jl)] = f2b_fast(sl);
        }
      }
    }
    // GEMM2 first k-step weights loaded BEFORE the barrier: latency hides
    const u16* qp = w2p + (((size_t)(wcol * 4) * 16 + ch * 4) * 64 + lane) * 8;
    bf16x8 d0 = *(const bf16x8*)(qp);
    bf16x8 d1 = *(const bf16x8*)(qp + 8192);      // o-block stride = 16*512
    bf16x8 d2 = *(const bf16x8*)(qp + 16384);
    bf16x8 d3 = *(const bf16x8*)(qp + 24576);
    __syncthreads();  // sHh ready
    // ---- GEMM2 partial: K = this 128-j chunk (4 k-steps) ----
#pragma unroll
    for (int k = 0; k < 4; ++k) {
      bf16x8 e0, e1, e2, e3;
      if (k < 3) {
        e0 = *(const bf16x8*)(qp + (size_t)(k + 1) * 512);
        e1 = *(const bf16x8*)(qp + 8192 + (size_t)(k + 1) * 512);
        e2 = *(const bf16x8*)(qp + 16384 + (size_t)(k + 1) * 512);
        e3 = *(const bf16x8*)(qp + 24576 + (size_t)(k + 1) * 512);
      }
      int col = k * 32 + lq * 8;
#pragma unroll
      for (int mi = 0; mi < 2; mi++) {
        bf16x8 a = *(const bf16x8*)&sHh[swzH((wrow * 2 + mi) * 16 + lm, col)];
        acc2[0][mi] = __builtin_amdgcn_mfma_f32_16x16x32_bf16(a, d0, acc2[0][mi], 0, 0, 0);
        acc2[1][mi] = __builtin_amdgcn_mfma_f32_16x16x32_bf16(a, d1, acc2[1][mi], 0, 0, 0);
        acc2[2][mi] = __builtin_amdgcn_mfma_f32_16x16x32_bf16(a, d2, acc2[2][mi], 0, 0, 0);
        acc2[3][mi] = __builtin_amdgcn_mfma_f32_16x16x32_bf16(a, d3, acc2[3][mi], 0, 0, 0);
      }
      if (k < 3) { d0 = e0; d1 = e1; d2 = e2; d3 = e3; }
    }
  }

  // ---- epilogue: out[c][s] = out1 + ff (bias already in acc2) ----
#pragma unroll
  for (int t = 0; t < 4; t++) {
    int c = (wcol * 4 + t) * 16 + lm;
#pragma unroll
    for (int mi = 0; mi < 2; mi++) {
      int sb = (wrow * 2 + mi) * 16 + lq * 4;
      f32x4 v = acc2[t][mi];
      float4 ov;
      ov.x = v[0] + b2f(sX[swz(sb + 0, c)]);
      ov.y = v[1] + b2f(sX[swz(sb + 1, c)]);
      ov.z = v[2] + b2f(sX[swz(sb + 2, c)]);
      ov.w = v[3] + b2f(sX[swz(sb + 3, c)]);
      *(float4*)(out + (((size_t)(b * QC + c)) << 14) + s0 + sb) = ov;
    }
  }
}

extern "C" void kernel_launch(void* const* d_in, const int* in_sizes, int n_in,
                              void* d_out, int out_size, void* d_ws, size_t ws_size,
                              hipStream_t stream) {
  const float* feat   = (const float*)d_in[0];
  const float* tokens = (const float*)d_in[1];
  const float* qw     = (const float*)d_in[2];
  const float* qb     = (const float*)d_in[3];
  const float* kw     = (const float*)d_in[4];
  const float* vw     = (const float*)d_in[5];
  const float* projw  = (const float*)d_in[6];
  const float* projb  = (const float*)d_in[7];
  const float* ff1w   = (const float*)d_in[8];
  const float* ff1b   = (const float*)d_in[9];
  const float* ff2w   = (const float*)d_in[10];
  const float* ff2b   = (const float*)d_in[11];
  const float* gate   = (const float*)d_in[12];
  float* out = (float*)d_out;

  // Workspace layout — total 1.125 MB (within proven envelope)
  u16* w1p = (u16*)d_ws;        // 256 KB @ 0
  u16* w2p = w1p + 131072;      // 256 KB @ 256K
  u16* qwp = w2p + 131072;      //  64 KB @ 512K
  u16* pwp = qwp + 32768;       //  64 KB @ 576K
  u16* Kbp = pwp + 32768;       // 256 KB @ 640K (K bf16 B-frag packed)
  u16* Vbp = Kbp + 131072;      // 256 KB @ 896K (V bf16 B-frag packed)

  prep_kernel<<<dim3(NB * NT), dim3(256), 0, stream>>>(
      ff1w, ff2w, w1p, w2p, qw, projw, qwp, pwp, tokens, kw, vw, gate,
      Kbp, Vbp);
  fused_kernel<<<dim3(NB * (SD / TSP)), dim3(512), 0, stream>>>(
      feat, qb, projb, ff1b, ff2b, w1p, w2p, qwp, pwp, gate, Kbp, Vbp, out);
}